// Round 5
// baseline (682.200 us; speedup 1.0000x reference)
//
#include <hip/hip_runtime.h>

typedef __bf16 bf16x8 __attribute__((ext_vector_type(8)));
typedef __bf16 bf16x4 __attribute__((ext_vector_type(4)));
typedef float f32x4 __attribute__((ext_vector_type(4)));

#define EMBED 584
#define KP 608      // K padded to 19*32 (zero-filled cols 584..607)
#define HEADS 8
#define HS 73
#define HSQ 80      // padded head size in q/k storage (16B-aligned rows)
#define CTX 200
#define NBATCH 256
#define MROWS 51200 // NBATCH*CTX
#define NQKV 1752   // 3*EMBED

// attention P-scratch stride (halfwords): 14 tiles*16 = 224 used + 8 pad.
#define PSS 232

// async global->LDS 16B copy: LDS dest is wave-uniform base + lane*16
__device__ __forceinline__ void gld_lds16(__bf16* lds, const __bf16* g) {
  __builtin_amdgcn_global_load_lds(
      (const __attribute__((address_space(1))) void*)g,
      (__attribute__((address_space(3))) void*)lds, 16, 0, 0);
}

// ---- fp32 -> bf16 convert x into padded [51200][608], 8 elems/thread ----
__global__ __launch_bounds__(256) void cvt_x(const float* __restrict__ x,
                                             __bf16* __restrict__ out) {
  int i = blockIdx.x * 256 + threadIdx.x;   // 15200*256 = 3,891,200 exact
  int r = i / 76, slot = i - r * 76;
  int col = slot * 8;
  bf16x8 o8 = {};
  if (col < EMBED) {
    const float4* s4 = (const float4*)(x + (size_t)r * EMBED + col);
    float4 f0 = s4[0], f1 = s4[1];
    o8[0] = (__bf16)f0.x; o8[1] = (__bf16)f0.y; o8[2] = (__bf16)f0.z; o8[3] = (__bf16)f0.w;
    o8[4] = (__bf16)f1.x; o8[5] = (__bf16)f1.y; o8[6] = (__bf16)f1.z; o8[7] = (__bf16)f1.w;
  }
  *(bf16x8*)(out + (size_t)r * KP + col) = o8;
}

// ---- pack Wq|Wk|Wv|Wo -> bf16 [2336][608] (zero pad cols) ----
__global__ __launch_bounds__(256) void pack_w(const float* __restrict__ Wq,
                                              const float* __restrict__ Wk,
                                              const float* __restrict__ Wv,
                                              const float* __restrict__ Wo,
                                              __bf16* __restrict__ out) {
  int i = blockIdx.x * 256 + threadIdx.x;
  if (i >= 2336 * 76) return;
  int r = i / 76, slot = i - r * 76;
  int col = slot * 8;
  bf16x8 o8 = {};
  if (col < EMBED) {
    const float* src = r < 584  ? Wq + (size_t)r * EMBED
                     : r < 1168 ? Wk + (size_t)(r - 584) * EMBED
                     : r < 1752 ? Wv + (size_t)(r - 1168) * EMBED
                                : Wo + (size_t)(r - 1752) * EMBED;
    const float4* s4 = (const float4*)(src + col);
    float4 f0 = s4[0], f1 = s4[1];
    o8[0] = (__bf16)f0.x; o8[1] = (__bf16)f0.y; o8[2] = (__bf16)f0.z; o8[3] = (__bf16)f0.w;
    o8[4] = (__bf16)f1.x; o8[5] = (__bf16)f1.y; o8[6] = (__bf16)f1.z; o8[7] = (__bf16)f1.w;
  }
  *(bf16x8*)(out + (size_t)r * KP + col) = o8;
}

// ---- zero the pad lanes attention reads directly from global ----
__global__ __launch_bounds__(256) void zero_pads(__bf16* __restrict__ qb,
                                                 __bf16* __restrict__ kb,
                                                 __bf16* __restrict__ vb) {
  int bh = blockIdx.x;
  bf16x8 z = {};
  __bf16* qp = qb + (size_t)bh * 16000;
  __bf16* kp = kb + (size_t)bh * 16000;
  __bf16* vp = vb + (size_t)bh * 16000;
  for (int i = threadIdx.x; i < 575; i += 256) {
    if (i < 200)      *(bf16x8*)&qp[i * 80 + 72] = z;
    else if (i < 400) *(bf16x8*)&kp[(i - 200) * 80 + 72] = z;
    else              *(bf16x8*)&vp[14600 + (i - 400) * 8] = z;
  }
}

// ---------------- QKV projection GEMM: C = A[M,KP] * B[N,KP]^T ------------
// 128x128 tile, 4 waves. A via LDS (2-buf, 16 KB); B-frags DIRECT from
// global into regs (weights are L2-hot per XCD) -- deletes B's LDS stage
// write + 4x-amplified LDS reads (DS pipe was the gate at ~60-90%).
// Split counted waits: vmcnt(4) pre-barrier retires only A(t) (B(t) stays
// in flight); vmcnt(2) pre-MFMA retires B(t) (A(t+1) stays in flight).
// B(t+1) loaded post-MFMA into same regs (no WAR; single-buffered).
// ~119 VGPR -> 4 waves/SIMD, LDS 16 KB -> 4 blocks/CU (2x TLP vs r4).
__global__ __launch_bounds__(256, 4) void gemm_qkv(const __bf16* __restrict__ A,
                                                   const __bf16* __restrict__ Bm,
                                                   __bf16* __restrict__ Q,
                                                   __bf16* __restrict__ Ko,
                                                   __bf16* __restrict__ V) {
  __shared__ __bf16 As[2][4096];   // [128][32] per buffer (8 KB)
  int tid = threadIdx.x;
  int id = blockIdx.x;
  int idp = (id & 7) * 700 + (id >> 3);    // 5600 = 8*700 bijective
  int bm = idp / 14, bn = idp - bm * 14;   // bn fast within a chunk
  int wid = tid >> 6, lane = tid & 63;
  int wm = (wid & 1) * 64, wn = (wid >> 1) * 64;
  int lr = lane & 15, lq = lane >> 4;
  int sw = ((lane & 3) ^ ((lane >> 2) & 3)) * 8;   // swizzled src col (A)
  const __bf16* aB = A + (size_t)(bm * 128 + wid * 32 + (lane >> 2)) * KP + sw;
  const __bf16* bp0 = Bm + (size_t)(bn * 128 + wn +  0 + lr) * KP + lq * 8;
  const __bf16* bp1 = Bm + (size_t)(bn * 128 + wn + 16 + lr) * KP + lq * 8;
  const __bf16* bp2 = Bm + (size_t)(bn * 128 + wn + 32 + lr) * KP + lq * 8;
  const __bf16* bp3 = Bm + (size_t)(bn * 128 + wn + 48 + lr) * KP + lq * 8;
  f32x4 acc[4][4] = {};
  bf16x8 bfr[4];

#define STAGE_A(buf, kt)                                          \
  do {                                                            \
    int k0_ = (kt) * 32;                                          \
    gld_lds16(As[buf] + wid * 1024,       aB + k0_);              \
    gld_lds16(As[buf] + wid * 1024 + 512, aB + 16 * KP + k0_);    \
  } while (0)
#define LOAD_B(kt)                                                \
  do {                                                            \
    bfr[0] = *(const bf16x8*)(bp0 + (kt) * 32);                   \
    bfr[1] = *(const bf16x8*)(bp1 + (kt) * 32);                   \
    bfr[2] = *(const bf16x8*)(bp2 + (kt) * 32);                   \
    bfr[3] = *(const bf16x8*)(bp3 + (kt) * 32);                   \
  } while (0)

  STAGE_A(0, 0);       // queue: A0[2] ...
  LOAD_B(0);           // ... B0[4]
  int cxr = (lq ^ (lr & 3)) * 8;   // swizzled LDS read col
#pragma unroll
  for (int kt = 0; kt < 19; ++kt) {
    // retire A(kt) (2 oldest); B(kt) stays in flight
    asm volatile("s_waitcnt vmcnt(4)" ::: "memory");
    __builtin_amdgcn_s_barrier();
    if (kt < 18) STAGE_A((kt + 1) & 1, kt + 1);
    const __bf16* Ac = As[kt & 1];
    bf16x8 af[4];
#pragma unroll
    for (int i = 0; i < 4; ++i)
      af[i] = *(const bf16x8*)&Ac[(wm + i * 16 + lr) * 32 + cxr];
    // retire B(kt); A(kt+1) stays in flight
    if (kt < 18) asm volatile("s_waitcnt vmcnt(2)" ::: "memory");
    else         asm volatile("s_waitcnt vmcnt(0)" ::: "memory");
    __builtin_amdgcn_s_setprio(1);
#pragma unroll
    for (int i = 0; i < 4; ++i)
#pragma unroll
      for (int j = 0; j < 4; ++j)
        acc[i][j] = __builtin_amdgcn_mfma_f32_16x16x32_bf16(af[i], bfr[j], acc[i][j], 0, 0, 0);
    __builtin_amdgcn_s_setprio(0);
    if (kt < 18) LOAD_B(kt + 1);   // post-MFMA: reuse regs, ~1 step slack
  }
#undef STAGE_A
#undef LOAD_B
  // ---- epilogue: slim index math ----
  int whichj[4], ojv[4];
  __bf16* Pj[4];
  bool okj[4];
#pragma unroll
  for (int j = 0; j < 4; ++j) {
    int n = bn * 128 + wn + j * 16 + lr;
    okj[j] = (n < NQKV);
    int nn = okj[j] ? n : 0;
    int which = nn / EMBED;
    int rem = nn - which * EMBED;
    int hh = rem / HS;
    int f = rem - hh * HS;
    whichj[j] = which;
    ojv[j] = (which == 2) ? (hh * 16000 + f * 200) : (hh * 16000 + f);
    Pj[j] = (which == 0) ? Q : (which == 1) ? Ko : V;
  }
#pragma unroll
  for (int i = 0; i < 4; ++i) {
    int m0 = bm * 128 + wm + i * 16 + lq * 4;  // multiple of 4
    int bb = m0 / CTX;
    int tt = m0 - bb * CTX;                    // multiple of 4 -> tt+3 <= 199
    int a_qk = bb * 128000 + tt * 80;
    int a_v  = bb * 128000 + tt;
#pragma unroll
    for (int j = 0; j < 4; ++j) {
      if (!okj[j]) continue;
      if (whichj[j] == 2) {
        bf16x4 v4;
#pragma unroll
        for (int r = 0; r < 4; ++r) v4[r] = (__bf16)acc[i][j][r];
        *(bf16x4*)&Pj[j][a_v + ojv[j]] = v4;   // 8B-aligned (tt%4==0)
      } else {
        int base = a_qk + ojv[j];
#pragma unroll
        for (int r = 0; r < 4; ++r)
          Pj[j][base + r * 80] = (__bf16)acc[i][j][r];
      }
    }
  }
}

// ---------------- MFMA flash attention: one block per (b,h) ---------------
// Barrier-free, single-pass-softmax, causality-skipping. (unchanged)
__global__ __launch_bounds__(256, 4) void attn_kernel(const __bf16* __restrict__ q,
                                                      const __bf16* __restrict__ k,
                                                      const __bf16* __restrict__ v,
                                                      __bf16* __restrict__ o) {
  __shared__ __align__(16) __bf16 Ps[4][16 * PSS];
  int tid = threadIdx.x;
  int bh = blockIdx.x;
  int b = bh >> 3, h = bh & 7;
  const __bf16* qg = q + (size_t)bh * 16000;
  const __bf16* kg = k + (size_t)bh * 16000;
  const __bf16* vg = v + (size_t)bh * 16000;

  if (h == 0) {
    bf16x8 z = {};
    for (int i = tid; i < CTX * 3; i += 256) {
      int t = i / 3, seg = i - t * 3;
      *(bf16x8*)&o[((size_t)(b * CTX + t)) * KP + EMBED + seg * 8] = z;
    }
  }

  int wid = tid >> 6, lane = tid & 63;
  int lr = lane & 15, g = lane >> 4;
  __bf16* Pw = Ps[wid];
  const float scale = 0.04138029443264672f;  // 584^-0.5

  int sl[4];
  sl[0] = 12 - wid;                   // 12,11,10,9
  sl[1] = (wid < 3) ? 6 + wid : 5;    // 6,7,8,5
  sl[2] = (wid < 3) ? 1 + wid : 4;    // 1,2,3,4
  sl[3] = (wid < 3) ? -1 : 0;         // -,-,-,0

#pragma unroll
  for (int si = 0; si < 4; ++si) {
    int s = sl[si];
    if (s < 0) continue;              // wave-uniform
    int row0 = s * 16;
    bf16x8 qf[3];
    qf[0] = *(const bf16x8*)&qg[(size_t)(row0 + lr) * HSQ + g * 8];
    qf[1] = *(const bf16x8*)&qg[(size_t)(row0 + lr) * HSQ + 32 + g * 8];
    qf[2] = (g < 2) ? *(const bf16x8*)&qg[(size_t)(row0 + lr) * HSQ + 64 + g * 8]
                    : bf16x8{};
    float sc[13][4];
#pragma unroll
    for (int nt = 0; nt < 13; ++nt) {
      if (nt > s) continue;           // wave-uniform skip
      f32x4 acc = {};
#pragma unroll
      for (int kc = 0; kc < 3; ++kc) {
        bf16x8 kf = *(const bf16x8*)&kg[(size_t)(nt * 16 + lr) * HSQ + kc * 32 + g * 8];
        acc = __builtin_amdgcn_mfma_f32_16x16x32_bf16(qf[kc], kf, acc, 0, 0, 0);
      }
#pragma unroll
      for (int r = 0; r < 4; ++r) {
        float val = acc[r] * scale;
        if (nt == s && lr > g * 4 + r) val = -1e30f;   // diagonal tile mask
        if (nt * 16 + lr >= CTX) val = -1e30f;         // keys beyond CTX
        sc[nt][r] = val;
      }
    }
    float mr[4], rs[4];
#pragma unroll
    for (int r = 0; r < 4; ++r) {
      float m = -1e30f;
#pragma unroll
      for (int nt = 0; nt < 13; ++nt)
        if (nt <= s) m = fmaxf(m, sc[nt][r]);
      mr[r] = m;
    }
#pragma unroll
    for (int off = 8; off; off >>= 1)
#pragma unroll
      for (int r = 0; r < 4; ++r)
        mr[r] = fmaxf(mr[r], __shfl_xor(mr[r], off, 64));
#pragma unroll
    for (int r = 0; r < 4; ++r) {
      float ssum = 0.f;
#pragma unroll
      for (int nt = 0; nt < 13; ++nt) {
        if (nt > s) continue;
        sc[nt][r] = __expf(sc[nt][r] - mr[r]);
        ssum += sc[nt][r];
      }
      rs[r] = ssum;
    }
#pragma unroll
    for (int off = 8; off; off >>= 1)
#pragma unroll
      for (int r = 0; r < 4; ++r) rs[r] += __shfl_xor(rs[r], off, 64);
#pragma unroll
    for (int nt = 0; nt < 13; ++nt) {
      if (nt > s) continue;
#pragma unroll
      for (int r = 0; r < 4; ++r)
        Pw[(g * 4 + r) * PSS + nt * 16 + lr] = (__bf16)sc[nt][r];
    }
    if ((s & 1) == 0) {
#pragma unroll
      for (int r = 0; r < 4; ++r)
        Pw[(g * 4 + r) * PSS + (s + 1) * 16 + lr] = (__bf16)0.f;
    }
    f32x4 ov[5];
#pragma unroll
    for (int nt = 0; nt < 5; ++nt) ov[nt] = f32x4{0.f, 0.f, 0.f, 0.f};
#pragma unroll
    for (int kc = 0; kc < 7; ++kc) {
      if (kc > s / 2) continue;       // only key tiles with nonzero P
      bf16x8 pf = *(const bf16x8*)&Pw[lr * PSS + kc * 32 + g * 8];
#pragma unroll
      for (int nt = 0; nt < 5; ++nt) {
        bf16x8 vf = *(const bf16x8*)&vg[(size_t)(nt * 16 + lr) * CTX + kc * 32 + g * 8];
        ov[nt] = __builtin_amdgcn_mfma_f32_16x16x32_bf16(pf, vf, ov[nt], 0, 0, 0);
      }
    }
    float inv[4];
#pragma unroll
    for (int r = 0; r < 4; ++r) inv[r] = 1.0f / rs[r];
#pragma unroll
    for (int nt = 0; nt < 5; ++nt) {
      int f = nt * 16 + lr;
      if (f < HS) {
#pragma unroll
        for (int r = 0; r < 4; ++r) {
          int t = row0 + g * 4 + r;
          if (t < CTX)
            o[((size_t)(b * CTX + t)) * KP + h * HS + f] =
                (__bf16)(ov[nt][r] * inv[r]);
        }
      }
    }
  }
}

// ---------------- output projection GEMM + bias, fp32 out -----------------
// Same A-via-LDS / B-direct structure; 2000 = 8*250 XCD-chunked.
// B rows read up to 1752+639 < 2336+vb: benign, store-guarded (n < 584).
__global__ __launch_bounds__(256, 4) void gemm_out(const __bf16* __restrict__ A,
                                                   const __bf16* __restrict__ Bm,
                                                   const float* __restrict__ bias,
                                                   float* __restrict__ C) {
  constexpr int N = EMBED;
  __shared__ __bf16 As[2][4096];
  int tid = threadIdx.x;
  int id = blockIdx.x;
  int idp = (id & 7) * 250 + (id >> 3);
  int bm = idp / 5, bn = idp - bm * 5;
  int wid = tid >> 6, lane = tid & 63;
  int wm = (wid & 1) * 64, wn = (wid >> 1) * 64;
  int lr = lane & 15, lq = lane >> 4;
  int sw = ((lane & 3) ^ ((lane >> 2) & 3)) * 8;
  const __bf16* aB = A + (size_t)(bm * 128 + wid * 32 + (lane >> 2)) * KP + sw;
  const __bf16* bp0 = Bm + (size_t)(bn * 128 + wn +  0 + lr) * KP + lq * 8;
  const __bf16* bp1 = Bm + (size_t)(bn * 128 + wn + 16 + lr) * KP + lq * 8;
  const __bf16* bp2 = Bm + (size_t)(bn * 128 + wn + 32 + lr) * KP + lq * 8;
  const __bf16* bp3 = Bm + (size_t)(bn * 128 + wn + 48 + lr) * KP + lq * 8;
  f32x4 acc[4][4] = {};
  bf16x8 bfr[4];

#define STAGE_A(buf, kt)                                          \
  do {                                                            \
    int k0_ = (kt) * 32;                                          \
    gld_lds16(As[buf] + wid * 1024,       aB + k0_);              \
    gld_lds16(As[buf] + wid * 1024 + 512, aB + 16 * KP + k0_);    \
  } while (0)
#define LOAD_B(kt)                                                \
  do {                                                            \
    bfr[0] = *(const bf16x8*)(bp0 + (kt) * 32);                   \
    bfr[1] = *(const bf16x8*)(bp1 + (kt) * 32);                   \
    bfr[2] = *(const bf16x8*)(bp2 + (kt) * 32);                   \
    bfr[3] = *(const bf16x8*)(bp3 + (kt) * 32);                   \
  } while (0)

  STAGE_A(0, 0);
  LOAD_B(0);
  int cxr = (lq ^ (lr & 3)) * 8;
#pragma unroll
  for (int kt = 0; kt < 19; ++kt) {
    asm volatile("s_waitcnt vmcnt(4)" ::: "memory");
    __builtin_amdgcn_s_barrier();
    if (kt < 18) STAGE_A((kt + 1) & 1, kt + 1);
    const __bf16* Ac = As[kt & 1];
    bf16x8 af[4];
#pragma unroll
    for (int i = 0; i < 4; ++i)
      af[i] = *(const bf16x8*)&Ac[(wm + i * 16 + lr) * 32 + cxr];
    if (kt < 18) asm volatile("s_waitcnt vmcnt(2)" ::: "memory");
    else         asm volatile("s_waitcnt vmcnt(0)" ::: "memory");
    __builtin_amdgcn_s_setprio(1);
#pragma unroll
    for (int i = 0; i < 4; ++i)
#pragma unroll
      for (int j = 0; j < 4; ++j)
        acc[i][j] = __builtin_amdgcn_mfma_f32_16x16x32_bf16(af[i], bfr[j], acc[i][j], 0, 0, 0);
    __builtin_amdgcn_s_setprio(0);
    if (kt < 18) LOAD_B(kt + 1);
  }
#undef STAGE_A
#undef LOAD_B
#pragma unroll
  for (int i = 0; i < 4; ++i) {
    int m = bm * 128 + wm + i * 16 + lq * 4;
#pragma unroll
    for (int j = 0; j < 4; ++j) {
      int n = bn * 128 + wn + j * 16 + lr;
      if (n < N) {
        float bval = bias[n];
#pragma unroll
        for (int r = 0; r < 4; ++r)
          C[(size_t)(m + r) * N + n] = acc[i][j][r] + bval;
      }
    }
  }
}

extern "C" void kernel_launch(void* const* d_in, const int* in_sizes, int n_in,
                              void* d_out, int out_size, void* d_ws, size_t ws_size,
                              hipStream_t stream) {
  const float* x  = (const float*)d_in[0];
  const float* Wq = (const float*)d_in[1];
  const float* Wk = (const float*)d_in[2];
  const float* Wv = (const float*)d_in[3];
  const float* Wo = (const float*)d_in[4];
  const float* bo = (const float*)d_in[5];
  float* out = (float*)d_out;

  // ws layout (bf16 elems), total 130,853,888 elems = 261.7 MB.
  __bf16* wcat = (__bf16*)d_ws;            // [2336*608]  = 1,420,288
  __bf16* vb   = wcat + 1420288ULL;        // [bh][f][200], 32,768,000
  __bf16* qb   = vb + 32768000ULL;         // [bh][t][80],  32,768,000
  __bf16* kb   = qb + 32768000ULL;         // [bh][t][80],  32,768,000
  __bf16* xb   = kb + 32768000ULL;         // [51200][608], 31,129,600
  __bf16* ab   = xb;  // alias: xb dead after gemm_qkv

  cvt_x<<<15200, 256, 0, stream>>>(x, xb);
  pack_w<<<694, 256, 0, stream>>>(Wq, Wk, Wv, Wo, wcat);
  zero_pads<<<2048, 256, 0, stream>>>(qb, kb, vb);
  gemm_qkv<<<5600, 256, 0, stream>>>(xb, wcat, qb, kb, vb);
  attn_kernel<<<2048, 256, 0, stream>>>(qb, kb, vb, ab);
  gemm_out<<<2000, 256, 0, stream>>>(ab, wcat + 1752ULL * KP, bo, out);
}

// Round 6
// 648.745 us; speedup vs baseline: 1.0516x; 1.0516x over previous
//
#include <hip/hip_runtime.h>

typedef __bf16 bf16x8 __attribute__((ext_vector_type(8)));
typedef __bf16 bf16x4 __attribute__((ext_vector_type(4)));
typedef float f32x4 __attribute__((ext_vector_type(4)));

#define EMBED 584
#define KP 608      // K padded to 19*32 (zero-filled cols 584..607)
#define HEADS 8
#define HS 73
#define HSQ 80      // padded head size in q/k storage (16B-aligned rows)
#define CTX 200
#define NBATCH 256
#define MROWS 51200 // NBATCH*CTX
#define NQKV 1752   // 3*EMBED

// attention P-scratch stride (halfwords): 14 tiles*16 = 224 used + 8 pad.
#define PSS 232

// async global->LDS 16B copy: LDS dest is wave-uniform base + lane*16
__device__ __forceinline__ void gld_lds16(__bf16* lds, const __bf16* g) {
  __builtin_amdgcn_global_load_lds(
      (const __attribute__((address_space(1))) void*)g,
      (__attribute__((address_space(3))) void*)lds, 16, 0, 0);
}

// ---- fp32 -> bf16 convert x into padded [51200][608], 8 elems/thread ----
__global__ __launch_bounds__(256) void cvt_x(const float* __restrict__ x,
                                             __bf16* __restrict__ out) {
  int i = blockIdx.x * 256 + threadIdx.x;   // 15200*256 = 3,891,200 exact
  int r = i / 76, slot = i - r * 76;
  int col = slot * 8;
  bf16x8 o8 = {};
  if (col < EMBED) {
    const float4* s4 = (const float4*)(x + (size_t)r * EMBED + col);
    float4 f0 = s4[0], f1 = s4[1];
    o8[0] = (__bf16)f0.x; o8[1] = (__bf16)f0.y; o8[2] = (__bf16)f0.z; o8[3] = (__bf16)f0.w;
    o8[4] = (__bf16)f1.x; o8[5] = (__bf16)f1.y; o8[6] = (__bf16)f1.z; o8[7] = (__bf16)f1.w;
  }
  *(bf16x8*)(out + (size_t)r * KP + col) = o8;
}

// ---- pack Wq|Wk|Wv|Wo -> bf16 [2336][608] (zero pad cols) ----
__global__ __launch_bounds__(256) void pack_w(const float* __restrict__ Wq,
                                              const float* __restrict__ Wk,
                                              const float* __restrict__ Wv,
                                              const float* __restrict__ Wo,
                                              __bf16* __restrict__ out) {
  int i = blockIdx.x * 256 + threadIdx.x;
  if (i >= 2336 * 76) return;
  int r = i / 76, slot = i - r * 76;
  int col = slot * 8;
  bf16x8 o8 = {};
  if (col < EMBED) {
    const float* src = r < 584  ? Wq + (size_t)r * EMBED
                     : r < 1168 ? Wk + (size_t)(r - 584) * EMBED
                     : r < 1752 ? Wv + (size_t)(r - 1168) * EMBED
                                : Wo + (size_t)(r - 1752) * EMBED;
    const float4* s4 = (const float4*)(src + col);
    float4 f0 = s4[0], f1 = s4[1];
    o8[0] = (__bf16)f0.x; o8[1] = (__bf16)f0.y; o8[2] = (__bf16)f0.z; o8[3] = (__bf16)f0.w;
    o8[4] = (__bf16)f1.x; o8[5] = (__bf16)f1.y; o8[6] = (__bf16)f1.z; o8[7] = (__bf16)f1.w;
  }
  *(bf16x8*)(out + (size_t)r * KP + col) = o8;
}

// ---- zero the pad lanes attention reads directly from global ----
__global__ __launch_bounds__(256) void zero_pads(__bf16* __restrict__ qb,
                                                 __bf16* __restrict__ kb,
                                                 __bf16* __restrict__ vb) {
  int bh = blockIdx.x;
  bf16x8 z = {};
  __bf16* qp = qb + (size_t)bh * 16000;
  __bf16* kp = kb + (size_t)bh * 16000;
  __bf16* vp = vb + (size_t)bh * 16000;
  for (int i = threadIdx.x; i < 575; i += 256) {
    if (i < 200)      *(bf16x8*)&qp[i * 80 + 72] = z;
    else if (i < 400) *(bf16x8*)&kp[(i - 200) * 80 + 72] = z;
    else              *(bf16x8*)&vp[14600 + (i - 400) * 8] = z;
  }
}

// ---------------- QKV projection GEMM: C = A[M,KP] * B[N,KP]^T ------------
// (r4 winner, restored verbatim: 194 us) 256x128 tile, 512 threads (8 waves),
// BK=32, 3-buffer stage-ahead-2, counted vmcnt(3), ONE s_barrier per K-step.
// Bank swizzle both-sides-consistent (G21). XCD chunked: 2800 = 8*350.
__global__ __launch_bounds__(512, 4) void gemm_qkv(const __bf16* __restrict__ A,
                                                   const __bf16* __restrict__ Bm,
                                                   __bf16* __restrict__ Q,
                                                   __bf16* __restrict__ Ko,
                                                   __bf16* __restrict__ V) {
  __shared__ __bf16 As[3][8192];   // [256][32] per buffer
  __shared__ __bf16 Bs[3][4096];   // [128][32]
  int tid = threadIdx.x;
  int id = blockIdx.x;
  int idp = (id & 7) * 350 + (id >> 3);
  int bm = idp / 14, bn = idp - bm * 14;   // bn fast within a chunk
  int wid = tid >> 6, lane = tid & 63;
  int wm = (wid & 3) * 64, wn = (wid >> 2) * 64;
  int lr = lane & 15, lq = lane >> 4;
  int sw = (((lane & 3) ^ ((lane >> 2) & 3))) * 8;   // swizzled src col
  const __bf16* aB = A  + (size_t)(bm * 256 + wid * 32 + (lane >> 2)) * KP + sw;
  const __bf16* bB = Bm + (size_t)(bn * 128 + wid * 16 + (lane >> 2)) * KP + sw;
  f32x4 acc[4][4] = {};

#define STAGE_QKV(buf, kt)                                        \
  do {                                                            \
    int k0_ = (kt) * 32;                                          \
    gld_lds16(As[buf] + wid * 1024,       aB + k0_);              \
    gld_lds16(As[buf] + wid * 1024 + 512, aB + 16 * KP + k0_);    \
    gld_lds16(Bs[buf] + wid * 512,        bB + k0_);              \
  } while (0)

  STAGE_QKV(0, 0);
  STAGE_QKV(1, 1);
  int cxr = (lq ^ (lr & 3)) * 8;   // swizzled read col for row R (R&3==lr&3)
#pragma unroll
  for (int kt = 0; kt < 19; ++kt) {
    if (kt < 18) asm volatile("s_waitcnt vmcnt(3)" ::: "memory");
    else         asm volatile("s_waitcnt vmcnt(0)" ::: "memory");
    __builtin_amdgcn_s_barrier();
    if (kt + 2 < 19) STAGE_QKV((kt + 2) % 3, kt + 2);
    const __bf16* Ac = As[kt % 3];
    const __bf16* Bc = Bs[kt % 3];
    bf16x8 af[4], bfr[4];
#pragma unroll
    for (int i = 0; i < 4; ++i)
      af[i] = *(const bf16x8*)&Ac[(wm + i * 16 + lr) * 32 + cxr];
#pragma unroll
    for (int j = 0; j < 4; ++j)
      bfr[j] = *(const bf16x8*)&Bc[(wn + j * 16 + lr) * 32 + cxr];
    __builtin_amdgcn_s_setprio(1);
#pragma unroll
    for (int i = 0; i < 4; ++i)
#pragma unroll
      for (int j = 0; j < 4; ++j)
        acc[i][j] = __builtin_amdgcn_mfma_f32_16x16x32_bf16(af[i], bfr[j], acc[i][j], 0, 0, 0);
    __builtin_amdgcn_s_setprio(0);
  }
#undef STAGE_QKV
  // ---- epilogue: slim index math ----
  int whichj[4], ojv[4];
  __bf16* Pj[4];
  bool okj[4];
#pragma unroll
  for (int j = 0; j < 4; ++j) {
    int n = bn * 128 + wn + j * 16 + lr;
    okj[j] = (n < NQKV);
    int nn = okj[j] ? n : 0;
    int which = nn / EMBED;
    int rem = nn - which * EMBED;
    int hh = rem / HS;
    int f = rem - hh * HS;
    whichj[j] = which;
    ojv[j] = (which == 2) ? (hh * 16000 + f * 200) : (hh * 16000 + f);
    Pj[j] = (which == 0) ? Q : (which == 1) ? Ko : V;
  }
#pragma unroll
  for (int i = 0; i < 4; ++i) {
    int m0 = bm * 256 + wm + i * 16 + lq * 4;  // multiple of 4
    int bb = m0 / CTX;
    int tt = m0 - bb * CTX;                    // multiple of 4 -> tt+3 <= 199
    int a_qk = bb * 128000 + tt * 80;
    int a_v  = bb * 128000 + tt;
#pragma unroll
    for (int j = 0; j < 4; ++j) {
      if (!okj[j]) continue;
      if (whichj[j] == 2) {
        bf16x4 v4;
#pragma unroll
        for (int r = 0; r < 4; ++r) v4[r] = (__bf16)acc[i][j][r];
        *(bf16x4*)&Pj[j][a_v + ojv[j]] = v4;   // 8B-aligned (tt%4==0)
      } else {
        int base = a_qk + ojv[j];
#pragma unroll
        for (int r = 0; r < 4; ++r)
          Pj[j][base + r * 80] = (__bf16)acc[i][j][r];
      }
    }
  }
}

// ---------------- MFMA flash attention: one block per (b,h) ---------------
// Barrier-free, causality-skipping, TWO-PASS softmax (max pass + recompute
// pass). Eliminates the sc[13][4] register array (peak live ~55 VGPR, no
// spill) -> LDS-capped 5 blocks/CU (20 waves) instead of ~3 spilling blocks.
// Pass 2's MFMA recompute is bitwise-identical to pass 1 (same inputs).
// Q,K: [bh][t][80] bf16 ; V: [bh][f][200] bf16 (transposed).
__global__ __launch_bounds__(256, 6) void attn_kernel(const __bf16* __restrict__ q,
                                                      const __bf16* __restrict__ k,
                                                      const __bf16* __restrict__ v,
                                                      __bf16* __restrict__ o) {
  __shared__ __align__(16) __bf16 Ps[4][16 * PSS];
  int tid = threadIdx.x;
  int bh = blockIdx.x;
  int b = bh >> 3, h = bh & 7;
  const __bf16* qg = q + (size_t)bh * 16000;
  const __bf16* kg = k + (size_t)bh * 16000;
  const __bf16* vg = v + (size_t)bh * 16000;

  // zero output pad columns (once per (b,t); h==0 blocks only)
  if (h == 0) {
    bf16x8 z = {};
    for (int i = tid; i < CTX * 3; i += 256) {
      int t = i / 3, seg = i - t * 3;
      *(bf16x8*)&o[((size_t)(b * CTX + t)) * KP + EMBED + seg * 8] = z;
    }
  }

  int wid = tid >> 6, lane = tid & 63;
  int lr = lane & 15, g = lane >> 4;
  __bf16* Pw = Ps[wid];
  const float scale = 0.04138029443264672f;  // 584^-0.5

  // balanced strip map: units(s)=s+1 -> totals {22,23,24,22}
  int sl[4];
  sl[0] = 12 - wid;                   // 12,11,10,9
  sl[1] = (wid < 3) ? 6 + wid : 5;    // 6,7,8,5
  sl[2] = (wid < 3) ? 1 + wid : 4;    // 1,2,3,4
  sl[3] = (wid < 3) ? -1 : 0;         // -,-,-,0

#pragma unroll
  for (int si = 0; si < 4; ++si) {
    int s = sl[si];
    if (s < 0) continue;              // wave-uniform
    int row0 = s * 16;
    // Q A-fragments direct from global: A[m=lr][k=g*8+j + kc*32]
    bf16x8 qf[3];
    qf[0] = *(const bf16x8*)&qg[(size_t)(row0 + lr) * HSQ + g * 8];
    qf[1] = *(const bf16x8*)&qg[(size_t)(row0 + lr) * HSQ + 32 + g * 8];
    qf[2] = (g < 2) ? *(const bf16x8*)&qg[(size_t)(row0 + lr) * HSQ + 64 + g * 8]
                    : bf16x8{};
    // ---- pass 1: QK^T, track row max only (scores discarded) ----
    float mr[4] = {-1e30f, -1e30f, -1e30f, -1e30f};
#pragma unroll
    for (int nt = 0; nt < 13; ++nt) {
      if (nt > s) continue;           // wave-uniform skip
      f32x4 acc = {};
#pragma unroll
      for (int kc = 0; kc < 3; ++kc) {
        bf16x8 kf = *(const bf16x8*)&kg[(size_t)(nt * 16 + lr) * HSQ + kc * 32 + g * 8];
        acc = __builtin_amdgcn_mfma_f32_16x16x32_bf16(qf[kc], kf, acc, 0, 0, 0);
      }
#pragma unroll
      for (int r = 0; r < 4; ++r) {
        float val = acc[r] * scale;
        if (nt == s && lr > g * 4 + r) val = -1e30f;   // diagonal tile mask
        if (nt * 16 + lr >= CTX) val = -1e30f;         // keys beyond CTX
        mr[r] = fmaxf(mr[r], val);
      }
    }
#pragma unroll
    for (int off = 8; off; off >>= 1)
#pragma unroll
      for (int r = 0; r < 4; ++r)
        mr[r] = fmaxf(mr[r], __shfl_xor(mr[r], off, 64));
    // ---- pass 2: recompute (bitwise-identical), exp, rowsum, P->LDS ----
    float rs[4] = {0.f, 0.f, 0.f, 0.f};
#pragma unroll
    for (int nt = 0; nt < 13; ++nt) {
      if (nt > s) continue;
      f32x4 acc = {};
#pragma unroll
      for (int kc = 0; kc < 3; ++kc) {
        bf16x8 kf = *(const bf16x8*)&kg[(size_t)(nt * 16 + lr) * HSQ + kc * 32 + g * 8];
        acc = __builtin_amdgcn_mfma_f32_16x16x32_bf16(qf[kc], kf, acc, 0, 0, 0);
      }
#pragma unroll
      for (int r = 0; r < 4; ++r) {
        float val = acc[r] * scale;
        if (nt == s && lr > g * 4 + r) val = -1e30f;
        if (nt * 16 + lr >= CTX) val = -1e30f;
        float p = __expf(val - mr[r]);
        rs[r] += p;
        Pw[(g * 4 + r) * PSS + nt * 16 + lr] = (__bf16)p;
      }
    }
#pragma unroll
    for (int off = 8; off; off >>= 1)
#pragma unroll
      for (int r = 0; r < 4; ++r) rs[r] += __shfl_xor(rs[r], off, 64);
    // zero odd tail tile (PV consumes key tiles in pairs)
    if ((s & 1) == 0) {
#pragma unroll
      for (int r = 0; r < 4; ++r)
        Pw[(g * 4 + r) * PSS + (s + 1) * 16 + lr] = (__bf16)0.f;
    }
    // ---- O = P V (V direct from global) ----
    f32x4 ov[5];
#pragma unroll
    for (int nt = 0; nt < 5; ++nt) ov[nt] = f32x4{0.f, 0.f, 0.f, 0.f};
#pragma unroll
    for (int kc = 0; kc < 7; ++kc) {
      if (kc > s / 2) continue;       // only key tiles with nonzero P
      bf16x8 pf = *(const bf16x8*)&Pw[lr * PSS + kc * 32 + g * 8];
#pragma unroll
      for (int nt = 0; nt < 5; ++nt) {
        bf16x8 vf = *(const bf16x8*)&vg[(size_t)(nt * 16 + lr) * CTX + kc * 32 + g * 8];
        ov[nt] = __builtin_amdgcn_mfma_f32_16x16x32_bf16(pf, vf, ov[nt], 0, 0, 0);
      }
    }
    // ---- store O / l ----
    float inv[4];
#pragma unroll
    for (int r = 0; r < 4; ++r) inv[r] = 1.0f / rs[r];
#pragma unroll
    for (int nt = 0; nt < 5; ++nt) {
      int f = nt * 16 + lr;
      if (f < HS) {
#pragma unroll
        for (int r = 0; r < 4; ++r) {
          int t = row0 + g * 4 + r;
          if (t < CTX)
            o[((size_t)(b * CTX + t)) * KP + h * HS + f] =
                (__bf16)(ov[nt][r] * inv[r]);
        }
      }
    }
  }
}

// ---------------- output projection GEMM + bias, fp32 out -----------------
// (r4 winner, restored verbatim) 256x128 8-wave 3-buffer; 1000 = 8*125.
__global__ __launch_bounds__(512, 4) void gemm_out(const __bf16* __restrict__ A,
                                                   const __bf16* __restrict__ Bm,
                                                   const float* __restrict__ bias,
                                                   float* __restrict__ C) {
  constexpr int N = EMBED;
  __shared__ __bf16 As[3][8192];
  __shared__ __bf16 Bs[3][4096];
  int tid = threadIdx.x;
  int id = blockIdx.x;
  int idp = (id & 7) * 125 + (id >> 3);
  int bm = idp / 5, bn = idp - bm * 5;
  int wid = tid >> 6, lane = tid & 63;
  int wm = (wid & 3) * 64, wn = (wid >> 2) * 64;
  int lr = lane & 15, lq = lane >> 4;
  int sw = (((lane & 3) ^ ((lane >> 2) & 3))) * 8;
  const __bf16* aB = A  + (size_t)(bm * 256 + wid * 32 + (lane >> 2)) * KP + sw;
  const __bf16* bB = Bm + (size_t)(bn * 128 + wid * 16 + (lane >> 2)) * KP + sw;
  f32x4 acc[4][4] = {};

#define STAGE_OUT(buf, kt)                                        \
  do {                                                            \
    int k0_ = (kt) * 32;                                          \
    gld_lds16(As[buf] + wid * 1024,       aB + k0_);              \
    gld_lds16(As[buf] + wid * 1024 + 512, aB + 16 * KP + k0_);    \
    gld_lds16(Bs[buf] + wid * 512,        bB + k0_);              \
  } while (0)

  STAGE_OUT(0, 0);
  STAGE_OUT(1, 1);
  int cxr = (lq ^ (lr & 3)) * 8;
#pragma unroll
  for (int kt = 0; kt < 19; ++kt) {
    if (kt < 18) asm volatile("s_waitcnt vmcnt(3)" ::: "memory");
    else         asm volatile("s_waitcnt vmcnt(0)" ::: "memory");
    __builtin_amdgcn_s_barrier();
    if (kt + 2 < 19) STAGE_OUT((kt + 2) % 3, kt + 2);
    const __bf16* Ac = As[kt % 3];
    const __bf16* Bc = Bs[kt % 3];
    bf16x8 af[4], bfr[4];
#pragma unroll
    for (int i = 0; i < 4; ++i)
      af[i] = *(const bf16x8*)&Ac[(wm + i * 16 + lr) * 32 + cxr];
#pragma unroll
    for (int j = 0; j < 4; ++j)
      bfr[j] = *(const bf16x8*)&Bc[(wn + j * 16 + lr) * 32 + cxr];
    __builtin_amdgcn_s_setprio(1);
#pragma unroll
    for (int i = 0; i < 4; ++i)
#pragma unroll
      for (int j = 0; j < 4; ++j)
        acc[i][j] = __builtin_amdgcn_mfma_f32_16x16x32_bf16(af[i], bfr[j], acc[i][j], 0, 0, 0);
    __builtin_amdgcn_s_setprio(0);
  }
#undef STAGE_OUT
#pragma unroll
  for (int i = 0; i < 4; ++i) {
    int m = bm * 256 + wm + i * 16 + lq * 4;
#pragma unroll
    for (int j = 0; j < 4; ++j) {
      int n = bn * 128 + wn + j * 16 + lr;
      if (n < N) {
        float bval = bias[n];
#pragma unroll
        for (int r = 0; r < 4; ++r)
          C[(size_t)(m + r) * N + n] = acc[i][j][r] + bval;
      }
    }
  }
}

extern "C" void kernel_launch(void* const* d_in, const int* in_sizes, int n_in,
                              void* d_out, int out_size, void* d_ws, size_t ws_size,
                              hipStream_t stream) {
  const float* x  = (const float*)d_in[0];
  const float* Wq = (const float*)d_in[1];
  const float* Wk = (const float*)d_in[2];
  const float* Wv = (const float*)d_in[3];
  const float* Wo = (const float*)d_in[4];
  const float* bo = (const float*)d_in[5];
  float* out = (float*)d_out;

  // ws layout (bf16 elems), total 130,853,888 elems = 261.7 MB.
  __bf16* wcat = (__bf16*)d_ws;            // [2336*608]  = 1,420,288
  __bf16* vb   = wcat + 1420288ULL;        // [bh][f][200], 32,768,000
  __bf16* qb   = vb + 32768000ULL;         // [bh][t][80],  32,768,000
  __bf16* kb   = qb + 32768000ULL;         // [bh][t][80],  32,768,000
  __bf16* xb   = kb + 32768000ULL;         // [51200][608], 31,129,600
  __bf16* ab   = xb;  // alias: xb dead after gemm_qkv

  cvt_x<<<15200, 256, 0, stream>>>(x, xb);
  pack_w<<<694, 256, 0, stream>>>(Wq, Wk, Wv, Wo, wcat);
  zero_pads<<<2048, 256, 0, stream>>>(qb, kb, vb);
  gemm_qkv<<<2800, 512, 0, stream>>>(xb, wcat, qb, kb, vb);
  attn_kernel<<<2048, 256, 0, stream>>>(qb, kb, vb, ab);
  gemm_out<<<1000, 512, 0, stream>>>(ab, wcat + 1752ULL * KP, bo, out);
}